// Round 1
// baseline (211.268 us; speedup 1.0000x reference)
//
#include <hip/hip_runtime.h>

// Tuples (k=2): x (B=4, n=512, f=128) f32 -> out (B, n*n, 2f)
// out[b, i*n+j, c] = (c < f) ? x[b,i,c] : x[b,j,c-f]
//
// Pure broadcast: 1.07 GB written, 1 MB read (L2-resident). Write-BW bound.
// All dims are powers of two -> shift/mask index math only.

#define BATCH 4
#define NROW  512      // n
#define FEAT  128      // f
// floats per output row = 2*FEAT = 256 -> 64 float4
// float4 per input row  = FEAT/4 = 32
// float4 per input batch = NROW*32 = 16384 = 2^14
// output float4 per batch = NROW*NROW*64 = 2^18 * 2^6 = 2^24

__global__ void __launch_bounds__(256) tuples_bcast_kernel(
    const float4* __restrict__ x, float4* __restrict__ out)
{
    const unsigned total4 = (unsigned)BATCH << 24;          // 67,108,864
    const unsigned stride = gridDim.x * blockDim.x;
    for (unsigned idx = blockIdx.x * blockDim.x + threadIdx.x;
         idx < total4; idx += stride)
    {
        unsigned c4 = idx & 63u;                 // float4 slot within output row
        unsigned t  = (idx >> 6) & ((NROW * NROW) - 1u); // tuple index i*n + j
        unsigned b  = idx >> 24;                 // batch
        // first half of row comes from i = t >> 9, second half from j = t & 511
        unsigned row  = (c4 < 32u) ? (t >> 9) : (t & (NROW - 1u));
        unsigned col4 = c4 & 31u;
        out[idx] = x[(b << 14) + (row << 5) + col4];
    }
}

extern "C" void kernel_launch(void* const* d_in, const int* in_sizes, int n_in,
                              void* d_out, int out_size, void* d_ws, size_t ws_size,
                              hipStream_t stream)
{
    const float4* x = (const float4*)d_in[0];
    float4* out = (float4*)d_out;
    // memory-bound: ~2048 blocks, grid-stride the rest (Guideline 11)
    tuples_bcast_kernel<<<2048, 256, 0, stream>>>(x, out);
}